// Round 1
// baseline (44.178 us; speedup 1.0000x reference)
//
#include <hip/hip_runtime.h>
#include <hip/hip_bf16.h>

// Problem constants (fixed by reference)
#define BB 4
#define LL 256
#define WW 256
#define HH 768
#define TL 4            // L-rows per block
#define HC 48           // h-chunk staged in LDS
#define NCH (HH / HC)   // 16 chunks
#define EPAD 52         // ea_s row stride in floats: 208B = 16B-aligned, bank-conflict-optimal
#define NL 10           // num labels

__global__ __launch_bounds__(256, 2) void wordkvmn_kernel(
    const int* __restrict__ word_seq,   // [B,W] int32
    const float* __restrict__ hidden,   // [B,L,H]
    const int* __restrict__ label,      // [B,L,W] int32
    const float* __restrict__ mask,     // [B,L,W]
    const float* __restrict__ emb_a,    // [50000,H]
    const float* __restrict__ emb_c,    // [10,H]
    float* __restrict__ out)            // [B,L,H]
{
    __shared__ float ea_s[WW][EPAD];    // 53248 B
    __shared__ float hid_s[TL][HC];     // 768 B
    __shared__ int   ws_s[WW];          // 1024 B
    __shared__ float s_lds[TL][NL];     // 160 B
    __shared__ float red[TL][4];        // 64 B

    const int t   = threadIdx.x;
    const int bid = blockIdx.x;
    const int b   = bid >> 6;           // / (L/TL)
    const int l0  = (bid & 63) * TL;

    if (t < WW) ws_s[t] = word_seq[b * WW + t];
    if (t < TL * NL) ((float*)s_lds)[t] = 0.0f;

    float u[TL] = {0.f, 0.f, 0.f, 0.f};

    for (int c = 0; c < NCH; ++c) {
        __syncthreads();  // ws_s ready (c==0) / ea_s consumed (c>0)

        // stage hidden chunk: TL*HC = 192 floats
        if (t < TL * HC) {
            int l = t / HC, h = t % HC;
            hid_s[l][h] = hidden[((size_t)(b * LL) + l0 + l) * HH + c * HC + h];
        }
        // stage gathered emb_a chunk: 256 rows x 48 floats = 3072 float4
        const int base_h = c * HC;
        #pragma unroll
        for (int p = 0; p < 12; ++p) {
            int f   = p * 256 + t;      // [0,3072)
            int w   = f / 12;
            int col = (f % 12) * 4;
            const float4 v = *reinterpret_cast<const float4*>(
                &emb_a[(size_t)ws_s[w] * HH + base_h + col]);
            *reinterpret_cast<float4*>(&ea_s[w][col]) = v;
        }
        __syncthreads();

        // accumulate u: thread t owns w=t, 4 L-rows
        #pragma unroll
        for (int hh = 0; hh < HC; hh += 4) {
            float4 e4 = *reinterpret_cast<const float4*>(&ea_s[t][hh]);
            #pragma unroll
            for (int l = 0; l < TL; ++l) {
                float4 h4 = *reinterpret_cast<const float4*>(&hid_s[l][hh]);
                u[l] = fmaf(h4.x, e4.x, u[l]);
                u[l] = fmaf(h4.y, e4.y, u[l]);
                u[l] = fmaf(h4.z, e4.z, u[l]);
                u[l] = fmaf(h4.w, e4.w, u[l]);
            }
        }
    }

    // masked exp
    const float scale = 0.03608439182435161f;  // 1/sqrt(768)
    float e[TL];
    #pragma unroll
    for (int l = 0; l < TL; ++l) {
        float m = mask[((size_t)(b * LL) + l0 + l) * WW + t];
        m = fminf(fmaxf(m, 0.f), 1.f);
        e[l] = __expf(u[l] * scale) * m;
    }

    // softmax denominator: reduce over 256 threads per l
    const int lane = t & 63, wid = t >> 6;
    #pragma unroll
    for (int l = 0; l < TL; ++l) {
        float r = e[l];
        #pragma unroll
        for (int off = 32; off; off >>= 1) r += __shfl_xor(r, off, 64);
        if (lane == 0) red[l][wid] = r;
    }
    __syncthreads();

    float p[TL];
    #pragma unroll
    for (int l = 0; l < TL; ++l) {
        float sum = red[l][0] + red[l][1] + red[l][2] + red[l][3] + 1e-10f;
        p[l] = e[l] / sum;
    }

    // bucket p by label into s[l][k]  (emb_c has only 10 rows!)
    #pragma unroll
    for (int l = 0; l < TL; ++l) {
        int k = label[((size_t)(b * LL) + l0 + l) * WW + t];
        atomicAdd(&s_lds[l][k], p[l]);
    }
    __syncthreads();

    // epilogue: o[l,h] = hidden[l,h] + sum_k s[l][k] * emb_c[k,h]
    #pragma unroll
    for (int j = 0; j < 3; ++j) {
        int h = j * 256 + t;
        float ec[NL];
        #pragma unroll
        for (int k = 0; k < NL; ++k) ec[k] = emb_c[k * HH + h];
        #pragma unroll
        for (int l = 0; l < TL; ++l) {
            size_t base = ((size_t)(b * LL) + l0 + l) * HH + h;
            float acc = hidden[base];
            #pragma unroll
            for (int k = 0; k < NL; ++k) acc = fmaf(s_lds[l][k], ec[k], acc);
            out[base] = acc;
        }
    }
}

extern "C" void kernel_launch(void* const* d_in, const int* in_sizes, int n_in,
                              void* d_out, int out_size, void* d_ws, size_t ws_size,
                              hipStream_t stream) {
    const int*   word_seq = (const int*)d_in[0];
    const float* hidden   = (const float*)d_in[1];
    const int*   label    = (const int*)d_in[2];
    const float* mask     = (const float*)d_in[3];
    const float* emb_a    = (const float*)d_in[4];
    const float* emb_c    = (const float*)d_in[5];
    float*       out      = (float*)d_out;

    wordkvmn_kernel<<<BB * (LL / TL), 256, 0, stream>>>(
        word_seq, hidden, label, mask, emb_a, emb_c, out);
}